// Round 1
// baseline (479.510 us; speedup 1.0000x reference)
//
#include <hip/hip_runtime.h>

#define B_SZ   32
#define N_SZ   8192
#define HDIM   256
#define GHID   512
#define K_CL   64
#define M_ROWS (B_SZ * (2 * K_CL + 1))   // 4128

// ---------------------------------------------------------------------------
// Kernel A: clustered row-sum. Hk[b,k,h] = sum_{p: cs[p]==k, p<n} hs[b,p,h]
// Grid: (B, N/128). Block: 256 threads = 64 float4-cols x 4 row-subsets of 32.
// Run-length accumulate in registers, flush with atomicAdd on cluster change.
// ---------------------------------------------------------------------------
__global__ __launch_bounds__(256) void cluster_sum_kernel(
    const float* __restrict__ hs, const int* __restrict__ cs,
    const int* __restrict__ n_ptr, float* __restrict__ Hk) {
  const int b = blockIdx.x;
  const int chunk = blockIdx.y;
  const int tid = threadIdx.x;
  const int col = (tid & 63) * 4;
  const int rsub = tid >> 6;
  const int n_val = n_ptr[0];
  const int row0 = chunk * 128 + rsub * 32;
  const float* hsb = hs + (size_t)b * N_SZ * HDIM;

  float4 acc = make_float4(0.f, 0.f, 0.f, 0.f);
  int cur = -1;
  bool has = false;
  for (int i = 0; i < 32; ++i) {
    const int p = row0 + i;
    const int c = (p < n_val) ? cs[p] : -1;
    if (c != cur) {
      if (has) {
        float* dst = Hk + ((size_t)b * K_CL + cur) * HDIM + col;
        atomicAdd(dst + 0, acc.x); atomicAdd(dst + 1, acc.y);
        atomicAdd(dst + 2, acc.z); atomicAdd(dst + 3, acc.w);
      }
      acc = make_float4(0.f, 0.f, 0.f, 0.f);
      cur = c; has = false;
    }
    if (c >= 0 && c < K_CL) {
      const float4 v = *(const float4*)(hsb + (size_t)p * HDIM + col);
      acc.x += v.x; acc.y += v.y; acc.z += v.z; acc.w += v.w;
      has = true;
    }
  }
  if (has && cur >= 0 && cur < K_CL) {
    float* dst = Hk + ((size_t)b * K_CL + cur) * HDIM + col;
    atomicAdd(dst + 0, acc.x); atomicAdd(dst + 1, acc.y);
    atomicAdd(dst + 2, acc.z); atomicAdd(dst + 3, acc.w);
  }
}

// ---------------------------------------------------------------------------
// Kernel B: build H = [Hk ; Hk + hn ; hn]  -> (B, 129, 256)
// Grid: (129, B), 256 threads (one column each).
// ---------------------------------------------------------------------------
__global__ __launch_bounds__(256) void build_H_kernel(
    const float* __restrict__ hs, const float* __restrict__ Hk,
    const int* __restrict__ n_ptr, float* __restrict__ H) {
  const int j = blockIdx.x;            // 0..128
  const int b = blockIdx.y;
  const int h = threadIdx.x;
  const int n_val = n_ptr[0];
  const float hn = hs[((size_t)b * N_SZ + n_val) * HDIM + h];
  float v;
  if (j < K_CL)            v = Hk[((size_t)b * K_CL + j) * HDIM + h];
  else if (j < 2 * K_CL)   v = Hk[((size_t)b * K_CL + (j - K_CL)) * HDIM + h] + hn;
  else                     v = hn;
  H[((size_t)b * (2 * K_CL + 1) + j) * HDIM + h] = v;
}

// ---------------------------------------------------------------------------
// fp32 tiled GEMM: C[M,N] = act(A[M,K] @ W[K,N] + bias), act = relu or id.
// BM=BN=64, BK=32, 256 threads, 4x4 acc per thread.
// ---------------------------------------------------------------------------
template <bool RELU>
__global__ __launch_bounds__(256) void gemm_bias_kernel(
    const float* __restrict__ A, const float* __restrict__ W,
    const float* __restrict__ bias, float* __restrict__ C,
    int M, int K, int N) {
  constexpr int BM = 64, BN = 64, BK = 32;
  __shared__ float As[BK][BM + 4];   // pad 4 floats: 16B-aligned rows, broken banks
  __shared__ float Ws[BK][BN];

  const int tid = threadIdx.x;
  const int rg = tid >> 4;           // 0..15 -> rows rg*4..+3
  const int cg = tid & 15;           // 0..15 -> cols cg*4..+3
  const int row0 = blockIdx.x * BM;
  const int col0 = blockIdx.y * BN;

  float acc[4][4] = {};

  for (int k0 = 0; k0 < K; k0 += BK) {
    // Stage A^T: thread t loads A[row0 + (t>>2)][k0 + (t&3)*8 .. +7]
    {
      const int r = tid >> 2;
      const int kk = (tid & 3) * 8;
      const int grow = row0 + r;
      float4 v0 = make_float4(0.f, 0.f, 0.f, 0.f), v1 = v0;
      if (grow < M) {
        const float* src = A + (size_t)grow * K + k0 + kk;
        v0 = *(const float4*)(src);
        v1 = *(const float4*)(src + 4);
      }
      As[kk + 0][r] = v0.x; As[kk + 1][r] = v0.y;
      As[kk + 2][r] = v0.z; As[kk + 3][r] = v0.w;
      As[kk + 4][r] = v1.x; As[kk + 5][r] = v1.y;
      As[kk + 6][r] = v1.z; As[kk + 7][r] = v1.w;
    }
    // Stage W tile: BK x BN
    for (int f = tid; f < BK * BN / 4; f += 256) {
      const int kk = f / (BN / 4);
      const int c = (f % (BN / 4)) * 4;
      *(float4*)&Ws[kk][c] = *(const float4*)(W + (size_t)(k0 + kk) * N + col0 + c);
    }
    __syncthreads();

#pragma unroll 8
    for (int kk = 0; kk < BK; ++kk) {
      const float4 a = *(const float4*)&As[kk][rg * 4];
      const float4 w = *(const float4*)&Ws[kk][cg * 4];
      acc[0][0] += a.x * w.x; acc[0][1] += a.x * w.y; acc[0][2] += a.x * w.z; acc[0][3] += a.x * w.w;
      acc[1][0] += a.y * w.x; acc[1][1] += a.y * w.y; acc[1][2] += a.y * w.z; acc[1][3] += a.y * w.w;
      acc[2][0] += a.z * w.x; acc[2][1] += a.z * w.y; acc[2][2] += a.z * w.z; acc[2][3] += a.z * w.w;
      acc[3][0] += a.w * w.x; acc[3][1] += a.w * w.y; acc[3][2] += a.w * w.z; acc[3][3] += a.w * w.w;
    }
    __syncthreads();
  }

  const float4 bv = *(const float4*)(bias + col0 + cg * 4);
#pragma unroll
  for (int i = 0; i < 4; ++i) {
    const int r = row0 + rg * 4 + i;
    if (r < M) {
      float4 o;
      o.x = acc[i][0] + bv.x; o.y = acc[i][1] + bv.y;
      o.z = acc[i][2] + bv.z; o.w = acc[i][3] + bv.w;
      if (RELU) {
        o.x = fmaxf(o.x, 0.f); o.y = fmaxf(o.y, 0.f);
        o.z = fmaxf(o.z, 0.f); o.w = fmaxf(o.w, 0.f);
      }
      *(float4*)(C + (size_t)r * N + col0 + cg * 4) = o;
    }
  }
}

// ---------------------------------------------------------------------------
// Combine: S = sum_{k<64} gs[b,k,:]; G[b,k] = S - gs[b,k] + gs[b,64+k];
// G[b,64] = S + gs[b,128]. Also writes the ones mask.
// Grid: B blocks, 256 threads (one column each).
// ---------------------------------------------------------------------------
__global__ __launch_bounds__(256) void combine_kernel(
    const float* __restrict__ gs, float* __restrict__ G, float* __restrict__ mask) {
  const int b = blockIdx.x;
  const int h = threadIdx.x;
  const float* g = gs + (size_t)b * (2 * K_CL + 1) * HDIM;
  float S = 0.f;
#pragma unroll 8
  for (int k = 0; k < K_CL; ++k) S += g[k * HDIM + h];
#pragma unroll 4
  for (int k = 0; k < K_CL; ++k) {
    G[((size_t)b * (K_CL + 1) + k) * HDIM + h] = S - g[k * HDIM + h] + g[(K_CL + k) * HDIM + h];
  }
  G[((size_t)b * (K_CL + 1) + K_CL) * HDIM + h] = S + g[2 * K_CL * HDIM + h];
  if (h < K_CL + 1) mask[b * (K_CL + 1) + h] = 1.0f;
}

extern "C" void kernel_launch(void* const* d_in, const int* in_sizes, int n_in,
                              void* d_out, int out_size, void* d_ws, size_t ws_size,
                              hipStream_t stream) {
  const float* hs = (const float*)d_in[0];
  const int* cs = (const int*)d_in[1];     // use row 0 (all rows identical semantics)
  const float* W1 = (const float*)d_in[2];
  const float* b1 = (const float*)d_in[3];
  const float* W2 = (const float*)d_in[4];
  const float* b2 = (const float*)d_in[5];
  const int* n_ptr = (const int*)d_in[6];

  float* G = (float*)d_out;                          // 32*65*256
  float* mask = G + (size_t)B_SZ * (K_CL + 1) * HDIM;

  float* Hk = (float*)d_ws;                          // 32*64*256
  float* H = Hk + (size_t)B_SZ * K_CL * HDIM;        // 32*129*256
  float* act = H + (size_t)B_SZ * (2 * K_CL + 1) * HDIM;  // 4128*512
  float* gs = act + (size_t)M_ROWS * GHID;           // 4128*256

  hipMemsetAsync(Hk, 0, (size_t)B_SZ * K_CL * HDIM * sizeof(float), stream);

  cluster_sum_kernel<<<dim3(B_SZ, N_SZ / 128), 256, 0, stream>>>(hs, cs, n_ptr, Hk);
  build_H_kernel<<<dim3(2 * K_CL + 1, B_SZ), 256, 0, stream>>>(hs, Hk, n_ptr, H);
  gemm_bias_kernel<true><<<dim3((M_ROWS + 63) / 64, GHID / 64), 256, 0, stream>>>(
      H, W1, b1, act, M_ROWS, HDIM, GHID);
  gemm_bias_kernel<false><<<dim3((M_ROWS + 63) / 64, HDIM / 64), 256, 0, stream>>>(
      act, W2, b2, gs, M_ROWS, GHID, HDIM);
  combine_kernel<<<B_SZ, 256, 0, stream>>>(gs, G, mask);
}